// Round 1
// baseline (829.488 us; speedup 1.0000x reference)
//
#include <hip/hip_runtime.h>

#define NN 100000
#define NU 60000
#define NE 1200000
#define DD 64

// in-degree via atomics (deg buffer pre-zeroed; +1 self-loop added in k_dinv)
__global__ void k_deg(const int* __restrict__ dst, float* __restrict__ deg, int ne) {
    int i = blockIdx.x * blockDim.x + threadIdx.x;
    if (i < ne) atomicAdd(&deg[dst[i]], 1.0f);
}

__global__ void k_dinv(float* __restrict__ deg, int n) {
    int i = blockIdx.x * blockDim.x + threadIdx.x;
    if (i < n) deg[i] = rsqrtf(deg[i] + 1.0f);
}

// H[n,64] = X[n,64] @ W[64,64].  Block = 256 threads = 4 rows x 64 cols.
// W staged in LDS (16 KB); Ws[k][c] access is 2-way bank aliased = free on gfx950.
__global__ __launch_bounds__(256) void k_gemm(const float* __restrict__ X,
                                              const float* __restrict__ W,
                                              float* __restrict__ H, int nrows) {
    __shared__ float Ws[64][64];
    __shared__ float Xs[4][64];
    for (int i = threadIdx.x; i < 64 * 64; i += 256) Ws[i >> 6][i & 63] = W[i];
    int c  = threadIdx.x & 63;
    int rl = threadIdx.x >> 6;
    int row = blockIdx.x * 4 + rl;
    if (row < nrows) Xs[rl][c] = X[row * 64 + c];
    __syncthreads();
    if (row >= nrows) return;
    float acc = 0.f;
#pragma unroll
    for (int k = 0; k < 64; ++k) acc += Xs[rl][k] * Ws[k][c];
    H[row * 64 + c] = acc;
}

// One wave per edge: lane = column. Coalesced 256B row gather; 64 atomics into agg[dst].
__global__ __launch_bounds__(256) void k_scatter(const float* __restrict__ H,
                                                 const int* __restrict__ src,
                                                 const int* __restrict__ dst,
                                                 const float* __restrict__ dinv,
                                                 float* __restrict__ agg, int ne) {
    int e = blockIdx.x * 4 + (threadIdx.x >> 6);
    if (e >= ne) return;
    int c = threadIdx.x & 63;
    int s = src[e], d = dst[e];
    float coef = dinv[s] * dinv[d];
    float v = H[s * 64 + c] * coef;
    atomicAdd(&agg[d * 64 + c], v);
}

// out = agg + H*dinv^2 + b [, relu].  In-place safe (same-index read/write).
__global__ void k_finalize(const float* __restrict__ agg, const float* __restrict__ H,
                           const float* __restrict__ dinv, const float* __restrict__ b,
                           float* __restrict__ out0, float* __restrict__ out1,
                           int n, int do_relu) {
    int i = blockIdx.x * blockDim.x + threadIdx.x;
    if (i >= n) return;
    int row = i >> 6, c = i & 63;
    float di = dinv[row];
    float v = agg[i] + H[i] * di * di + b[c];
    if (do_relu) v = fmaxf(v, 0.f);
    out0[i] = v;
    if (out1) out1[i] = v;
}

extern "C" void kernel_launch(void* const* d_in, const int* in_sizes, int n_in,
                              void* d_out, int out_size, void* d_ws, size_t ws_size,
                              hipStream_t stream) {
    const float* x  = (const float*)d_in[0];
    const int*   ei = (const int*)d_in[1];     // [2, NE] row-major: src then dst
    const float* W1 = (const float*)d_in[2];
    const float* b1 = (const float*)d_in[3];
    const float* W2 = (const float*)d_in[4];
    const float* b2 = (const float*)d_in[5];
    const int* src = ei;
    const int* dst = ei + NE;

    float* dinv = (float*)d_ws;                 // NN floats = 400 KB
    float* A = (float*)d_out;                   // NN*DD floats (25.6 MB) — out half 0
    float* B = (float*)d_out + (size_t)NN * DD; // out half 1

    // --- degree / dinv (shared by both layers) ---
    hipMemsetAsync(dinv, 0, NN * sizeof(float), stream);
    k_deg<<<(NE + 255) / 256, 256, 0, stream>>>(dst, dinv, NE);
    k_dinv<<<(NN + 255) / 256, 256, 0, stream>>>(dinv, NN);

    // --- layer 1: h1 = X@W1 -> A; agg -> B; h_relu -> A ---
    k_gemm<<<(NN + 3) / 4, 256, 0, stream>>>(x, W1, A, NN);
    hipMemsetAsync(B, 0, (size_t)NN * DD * sizeof(float), stream);
    k_scatter<<<(NE + 3) / 4, 256, 0, stream>>>(A, src, dst, dinv, B, NE);
    k_finalize<<<(NN * DD + 255) / 256, 256, 0, stream>>>(B, A, dinv, b1, A, nullptr, NN * DD, 1);

    // --- layer 2: h2 = A@W2 -> B; agg -> A; out -> both halves of d_out ---
    k_gemm<<<(NN + 3) / 4, 256, 0, stream>>>(A, W2, B, NN);
    hipMemsetAsync(A, 0, (size_t)NN * DD * sizeof(float), stream);
    k_scatter<<<(NE + 3) / 4, 256, 0, stream>>>(B, src, dst, dinv, A, NE);
    k_finalize<<<(NN * DD + 255) / 256, 256, 0, stream>>>(A, B, dinv, b2, A, B, NN * DD, 0);
}

// Round 2
// 713.058 us; speedup vs baseline: 1.1633x; 1.1633x over previous
//
#include <hip/hip_runtime.h>

#define NN 100000
#define NE 1200000
#define DD 64
#define SCAN_CH 256
#define SCAN_T ((NN + SCAN_CH - 1) / SCAN_CH)   // 391

// ---------------- degree / dinv ----------------
__global__ void k_hist(const int* __restrict__ dst, int* __restrict__ degi, int ne) {
    int i = blockIdx.x * blockDim.x + threadIdx.x;
    if (i < ne) atomicAdd(&degi[dst[i]], 1);
}

__global__ void k_dinv(const int* __restrict__ degi, float* __restrict__ dinv, int n) {
    int i = blockIdx.x * blockDim.x + threadIdx.x;
    if (i < n) dinv[i] = rsqrtf((float)degi[i] + 1.0f);
}

// ---------------- exclusive scan (3 kernels, 100k elems) ----------------
__global__ void k_scan1(const int* __restrict__ degi, int* __restrict__ partial) {
    int t = blockIdx.x * blockDim.x + threadIdx.x;
    if (t >= SCAN_T) return;
    int beg = t * SCAN_CH, end = min(beg + SCAN_CH, NN);
    int s = 0;
    for (int i = beg; i < end; ++i) s += degi[i];
    partial[t] = s;
}

__global__ __launch_bounds__(512) void k_scan2(int* __restrict__ partial, int* __restrict__ rowptr) {
    __shared__ int sm[512];
    int t = threadIdx.x;
    int v = (t < SCAN_T) ? partial[t] : 0;
    sm[t] = v;
    __syncthreads();
    for (int off = 1; off < 512; off <<= 1) {
        int add = (t >= off) ? sm[t - off] : 0;
        __syncthreads();
        sm[t] += add;
        __syncthreads();
    }
    if (t < SCAN_T) partial[t] = sm[t] - v;   // exclusive
    if (t == 0) rowptr[NN] = NE;
}

__global__ void k_scan3(const int* __restrict__ degi, const int* __restrict__ partial,
                        int* __restrict__ rowptr) {
    int t = blockIdx.x * blockDim.x + threadIdx.x;
    if (t >= SCAN_T) return;
    int beg = t * SCAN_CH, end = min(beg + SCAN_CH, NN);
    int run = partial[t];
    for (int i = beg; i < end; ++i) { rowptr[i] = run; run += degi[i]; }
}

// ---------------- CSR fill ----------------
__global__ void k_fill(const int* __restrict__ src, const int* __restrict__ dst,
                       const int* __restrict__ rowptr, int* __restrict__ cnt,
                       int* __restrict__ csr_src, int ne) {
    int e = blockIdx.x * blockDim.x + threadIdx.x;
    if (e >= ne) return;
    int d = dst[e];
    int pos = rowptr[d] + atomicAdd(&cnt[d], 1);
    csr_src[pos] = src[e];
}

// ---------------- GEMM: H[n,64] = X[n,64] @ W[64,64], 32 rows/block ----------------
// In-place safe (X==H): each block stages its own 32 rows into LDS before writing.
__global__ __launch_bounds__(256) void k_gemm(const float* __restrict__ X,
                                              const float* __restrict__ W,
                                              float* __restrict__ H, int nrows) {
    __shared__ float Ws[64][64];
    __shared__ float Xs[32][64];
    int tid = threadIdx.x;
    for (int i = tid; i < 64 * 64; i += 256) Ws[i >> 6][i & 63] = W[i];
    int row0 = blockIdx.x * 32;
    for (int i = tid; i < 32 * 64; i += 256) {
        int r = row0 + (i >> 6);
        Xs[i >> 6][i & 63] = (r < nrows) ? X[r * 64 + (i & 63)] : 0.f;
    }
    __syncthreads();
    int c = tid & 63;
    int wv = tid >> 6;            // wave 0..3 -> rows wv*8 .. wv*8+7
    float acc[8];
#pragma unroll
    for (int r = 0; r < 8; ++r) acc[r] = 0.f;
#pragma unroll
    for (int k = 0; k < 64; ++k) {
        float wk = Ws[k][c];
#pragma unroll
        for (int r = 0; r < 8; ++r) acc[r] += Xs[wv * 8 + r][k] * wk;
    }
#pragma unroll
    for (int r = 0; r < 8; ++r) {
        int row = row0 + wv * 8 + r;
        if (row < nrows) H[row * 64 + c] = acc[r];
    }
}

// ---------------- fused gather-reduce + self-loop + bias (+relu) ----------------
// One wave per dst node, lane = column.
__global__ __launch_bounds__(256) void k_reduce(const float* __restrict__ H,
                                                const int* __restrict__ rowptr,
                                                const int* __restrict__ csr_src,
                                                const float* __restrict__ dinv,
                                                const float* __restrict__ b,
                                                float* __restrict__ out,
                                                int do_relu) {
    int n = blockIdx.x * 4 + (threadIdx.x >> 6);
    if (n >= NN) return;
    int c = threadIdx.x & 63;
    float din = dinv[n];
    float acc = H[n * 64 + c] * din * din;     // self loop
    int e = rowptr[n], end = rowptr[n + 1];
    for (; e + 1 < end; e += 2) {
        int s0 = csr_src[e], s1 = csr_src[e + 1];
        float c0 = dinv[s0] * din, c1 = dinv[s1] * din;
        float v0 = H[s0 * 64 + c], v1 = H[s1 * 64 + c];
        acc += v0 * c0;
        acc += v1 * c1;
    }
    if (e < end) {
        int s0 = csr_src[e];
        acc += H[s0 * 64 + c] * (dinv[s0] * din);
    }
    float v = acc + b[c];
    if (do_relu) v = fmaxf(v, 0.f);
    out[n * 64 + c] = v;
}

__global__ void k_copy4(const float4* __restrict__ in, float4* __restrict__ out, int n4) {
    int i = blockIdx.x * blockDim.x + threadIdx.x;
    if (i < n4) out[i] = in[i];
}

// ---------------- fallback (round-1 atomic path, needs only 400KB ws) ----------------
__global__ void k_degf(const int* __restrict__ dst, float* __restrict__ deg, int ne) {
    int i = blockIdx.x * blockDim.x + threadIdx.x;
    if (i < ne) atomicAdd(&deg[dst[i]], 1.0f);
}
__global__ void k_dinvf(float* __restrict__ deg, int n) {
    int i = blockIdx.x * blockDim.x + threadIdx.x;
    if (i < n) deg[i] = rsqrtf(deg[i] + 1.0f);
}
__global__ __launch_bounds__(256) void k_scatter(const float* __restrict__ H,
                                                 const int* __restrict__ src,
                                                 const int* __restrict__ dst,
                                                 const float* __restrict__ dinv,
                                                 float* __restrict__ agg, int ne) {
    int e = blockIdx.x * 4 + (threadIdx.x >> 6);
    if (e >= ne) return;
    int c = threadIdx.x & 63;
    int s = src[e], d = dst[e];
    atomicAdd(&agg[d * 64 + c], H[s * 64 + c] * (dinv[s] * dinv[d]));
}
__global__ void k_finalize(const float* __restrict__ agg, const float* __restrict__ H,
                           const float* __restrict__ dinv, const float* __restrict__ b,
                           float* __restrict__ out0, float* __restrict__ out1,
                           int n, int do_relu) {
    int i = blockIdx.x * blockDim.x + threadIdx.x;
    if (i >= n) return;
    int row = i >> 6, c = i & 63;
    float di = dinv[row];
    float v = agg[i] + H[i] * di * di + b[c];
    if (do_relu) v = fmaxf(v, 0.f);
    out0[i] = v;
    if (out1) out1[i] = v;
}

extern "C" void kernel_launch(void* const* d_in, const int* in_sizes, int n_in,
                              void* d_out, int out_size, void* d_ws, size_t ws_size,
                              hipStream_t stream) {
    const float* x  = (const float*)d_in[0];
    const int*   ei = (const int*)d_in[1];     // [2, NE]: src row then dst row
    const float* W1 = (const float*)d_in[2];
    const float* b1 = (const float*)d_in[3];
    const float* W2 = (const float*)d_in[4];
    const float* b2 = (const float*)d_in[5];
    const int* src = ei;
    const int* dst = ei + NE;

    float* A = (float*)d_out;                   // half 0 (user+movie view = h)
    float* B = (float*)d_out + (size_t)NN * DD; // half 1 (h view)

    // ws layout
    char* w = (char*)d_ws;
    size_t off = 0;
    auto alloc = [&](size_t bytes) { void* p = w + off; off += (bytes + 255) & ~(size_t)255; return p; };
    float* dinv   = (float*)alloc(NN * sizeof(float));
    int*   degi   = (int*)  alloc(NN * sizeof(int));
    int*   cnt    = (int*)  alloc(NN * sizeof(int));
    int*   rowptr = (int*)  alloc((NN + 1) * sizeof(int));
    int*   part   = (int*)  alloc(512 * sizeof(int));
    int*   csr    = (int*)  alloc(NE * sizeof(int));

    if (ws_size >= off) {
        // ---- CSR build ----
        hipMemsetAsync(degi, 0, NN * sizeof(int), stream);
        hipMemsetAsync(cnt, 0, NN * sizeof(int), stream);
        k_hist<<<(NE + 255) / 256, 256, 0, stream>>>(dst, degi, NE);
        k_dinv<<<(NN + 255) / 256, 256, 0, stream>>>(degi, dinv, NN);
        k_scan1<<<(SCAN_T + 255) / 256, 256, 0, stream>>>(degi, part);
        k_scan2<<<1, 512, 0, stream>>>(part, rowptr);
        k_scan3<<<(SCAN_T + 255) / 256, 256, 0, stream>>>(degi, part, rowptr);
        k_fill<<<(NE + 255) / 256, 256, 0, stream>>>(src, dst, rowptr, cnt, csr, NE);

        // ---- layer 1: A = x@W1 ; B = relu(aggregate(A)+b1) ----
        k_gemm<<<(NN + 31) / 32, 256, 0, stream>>>(x, W1, A, NN);
        k_reduce<<<(NN + 3) / 4, 256, 0, stream>>>(A, rowptr, csr, dinv, b1, B, 1);

        // ---- layer 2: B = B@W2 (in-place) ; A = aggregate(B)+b2 ; B = A ----
        k_gemm<<<(NN + 31) / 32, 256, 0, stream>>>(B, W2, B, NN);
        k_reduce<<<(NN + 3) / 4, 256, 0, stream>>>(B, rowptr, csr, dinv, b2, A, 0);
        k_copy4<<<(NN * DD / 4 + 255) / 256, 256, 0, stream>>>((const float4*)A, (float4*)B, NN * DD / 4);
    } else {
        // ---- fallback: atomic scatter path ----
        hipMemsetAsync(dinv, 0, NN * sizeof(float), stream);
        k_degf<<<(NE + 255) / 256, 256, 0, stream>>>(dst, dinv, NE);
        k_dinvf<<<(NN + 255) / 256, 256, 0, stream>>>(dinv, NN);
        k_gemm<<<(NN + 31) / 32, 256, 0, stream>>>(x, W1, A, NN);
        hipMemsetAsync(B, 0, (size_t)NN * DD * sizeof(float), stream);
        k_scatter<<<(NE + 3) / 4, 256, 0, stream>>>(A, src, dst, dinv, B, NE);
        k_finalize<<<(NN * DD + 255) / 256, 256, 0, stream>>>(B, A, dinv, b1, A, nullptr, NN * DD, 1);
        k_gemm<<<(NN + 31) / 32, 256, 0, stream>>>(A, W2, B, NN);
        hipMemsetAsync(A, 0, (size_t)NN * DD * sizeof(float), stream);
        k_scatter<<<(NE + 3) / 4, 256, 0, stream>>>(B, src, dst, dinv, A, NE);
        k_finalize<<<(NN * DD + 255) / 256, 256, 0, stream>>>(A, B, dinv, b2, A, B, NN * DD, 0);
    }
}

// Round 3
// 468.550 us; speedup vs baseline: 1.7703x; 1.5218x over previous
//
#include <hip/hip_runtime.h>

#define NN 100000
#define NE 1200000
#define DD 64
#define SCAN_CH 256
#define SCAN_T ((NN + SCAN_CH - 1) / SCAN_CH)   // 391

// bf16 helpers (round-to-nearest-even)
static __device__ __forceinline__ unsigned short f2bf(float f) {
    unsigned int u = __float_as_uint(f);
    u += 0x7fffu + ((u >> 16) & 1u);
    return (unsigned short)(u >> 16);
}
static __device__ __forceinline__ float bf2f(unsigned short h) {
    return __uint_as_float(((unsigned int)h) << 16);
}

// ---------------- degree / dinv ----------------
__global__ void k_hist(const int* __restrict__ dst, int* __restrict__ degi, int ne) {
    int i = blockIdx.x * blockDim.x + threadIdx.x;
    if (i < ne) atomicAdd(&degi[dst[i]], 1);
}

__global__ void k_dinv(const int* __restrict__ degi, float* __restrict__ dinv, int n) {
    int i = blockIdx.x * blockDim.x + threadIdx.x;
    if (i < n) dinv[i] = rsqrtf((float)degi[i] + 1.0f);
}

// ---------------- exclusive scan (3 kernels) ----------------
__global__ void k_scan1(const int* __restrict__ degi, int* __restrict__ partial) {
    int t = blockIdx.x * blockDim.x + threadIdx.x;
    if (t >= SCAN_T) return;
    int beg = t * SCAN_CH, end = min(beg + SCAN_CH, NN);
    int s = 0;
    for (int i = beg; i < end; ++i) s += degi[i];
    partial[t] = s;
}

__global__ __launch_bounds__(512) void k_scan2(int* __restrict__ partial, int* __restrict__ rowptr) {
    __shared__ int sm[512];
    int t = threadIdx.x;
    int v = (t < SCAN_T) ? partial[t] : 0;
    sm[t] = v;
    __syncthreads();
    for (int off = 1; off < 512; off <<= 1) {
        int add = (t >= off) ? sm[t - off] : 0;
        __syncthreads();
        sm[t] += add;
        __syncthreads();
    }
    if (t < SCAN_T) partial[t] = sm[t] - v;   // exclusive
    if (t == 0) rowptr[NN] = NE;
}

__global__ void k_scan3(const int* __restrict__ degi, const int* __restrict__ partial,
                        int* __restrict__ rowptr) {
    int t = blockIdx.x * blockDim.x + threadIdx.x;
    if (t >= SCAN_T) return;
    int beg = t * SCAN_CH, end = min(beg + SCAN_CH, NN);
    int run = partial[t];
    for (int i = beg; i < end; ++i) { rowptr[i] = run; run += degi[i]; }
}

// ---------------- CSR fill ----------------
__global__ void k_fill(const int* __restrict__ src, const int* __restrict__ dst,
                       const int* __restrict__ rowptr, int* __restrict__ cnt,
                       int* __restrict__ csr_src, int ne) {
    int e = blockIdx.x * blockDim.x + threadIdx.x;
    if (e >= ne) return;
    int d = dst[e];
    int pos = rowptr[d] + atomicAdd(&cnt[d], 1);
    csr_src[pos] = src[e];
}

// ---------------- GEMM: Hb_bf16[n,64] = X[n,64] @ W[64,64] ----------------
// 64 rows/block; thread = 4 rows x 4 cols (16 FMA / k-step, ~2B LDS per FMA).
// Xs padded to 68 floats/row: conflict-free b32 reads (16B-aligned float4 staging).
__global__ __launch_bounds__(256) void k_gemm_bf(const float* __restrict__ X,
                                                 const float* __restrict__ W,
                                                 unsigned short* __restrict__ Hb,
                                                 int nrows) {
    __shared__ float4 Ws4[64][16];      // 16 KB: W[k][c4]
    __shared__ float  Xs[64][68];       // 17.4 KB, padded stride
    int tid = threadIdx.x;
    const float4* W4 = (const float4*)W;
    for (int i = tid; i < 64 * 16; i += 256) Ws4[i >> 4][i & 15] = W4[i];
    int row0 = blockIdx.x * 64;
    const float4* X4 = (const float4*)X;
    for (int i = tid; i < 64 * 16; i += 256) {
        int r = i >> 4, q = i & 15;
        int row = row0 + r;
        float4 v = make_float4(0.f, 0.f, 0.f, 0.f);
        if (row < nrows) v = X4[row * 16 + q];
        *((float4*)&Xs[r][q * 4]) = v;
    }
    __syncthreads();
    int c4 = tid & 15;          // col group (4 cols)
    int rg = tid >> 4;          // row group (4 rows)
    float4 acc0 = make_float4(0.f, 0.f, 0.f, 0.f);
    float4 acc1 = acc0, acc2 = acc0, acc3 = acc0;
#pragma unroll 4
    for (int k = 0; k < 64; ++k) {
        float4 w = Ws4[k][c4];
        float x0 = Xs[rg * 4 + 0][k];
        float x1 = Xs[rg * 4 + 1][k];
        float x2 = Xs[rg * 4 + 2][k];
        float x3 = Xs[rg * 4 + 3][k];
        acc0.x += x0 * w.x; acc0.y += x0 * w.y; acc0.z += x0 * w.z; acc0.w += x0 * w.w;
        acc1.x += x1 * w.x; acc1.y += x1 * w.y; acc1.z += x1 * w.z; acc1.w += x1 * w.w;
        acc2.x += x2 * w.x; acc2.y += x2 * w.y; acc2.z += x2 * w.z; acc2.w += x2 * w.w;
        acc3.x += x3 * w.x; acc3.y += x3 * w.y; acc3.z += x3 * w.z; acc3.w += x3 * w.w;
    }
    float4 accs[4] = {acc0, acc1, acc2, acc3};
#pragma unroll
    for (int i = 0; i < 4; ++i) {
        int row = row0 + rg * 4 + i;
        if (row < nrows) {
            ushort4 o;
            o.x = f2bf(accs[i].x); o.y = f2bf(accs[i].y);
            o.z = f2bf(accs[i].z); o.w = f2bf(accs[i].w);
            *((ushort4*)&Hb[row * 64 + c4 * 4]) = o;
        }
    }
}

// ---------------- fused gather-reduce + self-loop + bias (+relu) ----------------
// One wave per dst node, lane = column; bf16 gather source (128B rows); 4-edge unroll.
__global__ __launch_bounds__(256) void k_reduce(const unsigned short* __restrict__ Hb,
                                                const int* __restrict__ rowptr,
                                                const int* __restrict__ csr_src,
                                                const float* __restrict__ dinv,
                                                const float* __restrict__ b,
                                                float* __restrict__ out,
                                                int do_relu) {
    int n = blockIdx.x * 4 + (threadIdx.x >> 6);
    if (n >= NN) return;
    int c = threadIdx.x & 63;
    float din = dinv[n];
    float acc = bf2f(Hb[n * 64 + c]) * din * din;     // self loop
    int e = rowptr[n], end = rowptr[n + 1];
    for (; e + 3 < end; e += 4) {
        int s0 = csr_src[e], s1 = csr_src[e + 1], s2 = csr_src[e + 2], s3 = csr_src[e + 3];
        float v0 = bf2f(Hb[s0 * 64 + c]);
        float v1 = bf2f(Hb[s1 * 64 + c]);
        float v2 = bf2f(Hb[s2 * 64 + c]);
        float v3 = bf2f(Hb[s3 * 64 + c]);
        float c0 = dinv[s0] * din, c1 = dinv[s1] * din;
        float c2 = dinv[s2] * din, c3 = dinv[s3] * din;
        acc += v0 * c0; acc += v1 * c1; acc += v2 * c2; acc += v3 * c3;
    }
    for (; e < end; ++e) {
        int s0 = csr_src[e];
        acc += bf2f(Hb[s0 * 64 + c]) * (dinv[s0] * din);
    }
    float v = acc + b[c];
    if (do_relu) v = fmaxf(v, 0.f);
    out[n * 64 + c] = v;
}

__global__ void k_copy4(const float4* __restrict__ in, float4* __restrict__ out, int n4) {
    int i = blockIdx.x * blockDim.x + threadIdx.x;
    if (i < n4) out[i] = in[i];
}

extern "C" void kernel_launch(void* const* d_in, const int* in_sizes, int n_in,
                              void* d_out, int out_size, void* d_ws, size_t ws_size,
                              hipStream_t stream) {
    const float* x  = (const float*)d_in[0];
    const int*   ei = (const int*)d_in[1];     // [2, NE]: src row then dst row
    const float* W1 = (const float*)d_in[2];
    const float* b1 = (const float*)d_in[3];
    const float* W2 = (const float*)d_in[4];
    const float* b2 = (const float*)d_in[5];
    const int* src = ei;
    const int* dst = ei + NE;

    float* A = (float*)d_out;                   // half 0: final h (user+movie)
    float* B = (float*)d_out + (size_t)NN * DD; // half 1: final h; bf16 scratch meanwhile
    unsigned short* Bb = (unsigned short*)B;    // bf16 gather buffer (12.8 MB of half 1)

    // ws layout (~6.5 MB)
    char* w = (char*)d_ws;
    size_t off = 0;
    auto alloc = [&](size_t bytes) { void* p = w + off; off += (bytes + 255) & ~(size_t)255; return p; };
    float* dinv   = (float*)alloc(NN * sizeof(float));
    int*   degi   = (int*)  alloc(NN * sizeof(int));
    int*   cnt    = (int*)  alloc(NN * sizeof(int));
    int*   rowptr = (int*)  alloc((NN + 1) * sizeof(int));
    int*   part   = (int*)  alloc(512 * sizeof(int));
    int*   csr    = (int*)  alloc(NE * sizeof(int));
    (void)ws_size;

    // ---- CSR build ----
    hipMemsetAsync(degi, 0, NN * sizeof(int), stream);
    hipMemsetAsync(cnt, 0, NN * sizeof(int), stream);
    k_hist<<<(NE + 255) / 256, 256, 0, stream>>>(dst, degi, NE);
    k_dinv<<<(NN + 255) / 256, 256, 0, stream>>>(degi, dinv, NN);
    k_scan1<<<(SCAN_T + 255) / 256, 256, 0, stream>>>(degi, part);
    k_scan2<<<1, 512, 0, stream>>>(part, rowptr);
    k_scan3<<<(SCAN_T + 255) / 256, 256, 0, stream>>>(degi, part, rowptr);
    k_fill<<<(NE + 255) / 256, 256, 0, stream>>>(src, dst, rowptr, cnt, csr, NE);

    // ---- layer 1: Bb = bf16(x@W1); A = relu(agg(Bb)+b1) ----
    k_gemm_bf<<<(NN + 63) / 64, 256, 0, stream>>>(x, W1, Bb, NN);
    k_reduce<<<(NN + 3) / 4, 256, 0, stream>>>(Bb, rowptr, csr, dinv, b1, A, 1);

    // ---- layer 2: Bb = bf16(A@W2); A = agg(Bb)+b2; B = A ----
    k_gemm_bf<<<(NN + 63) / 64, 256, 0, stream>>>(A, W2, Bb, NN);
    k_reduce<<<(NN + 3) / 4, 256, 0, stream>>>(Bb, rowptr, csr, dinv, b2, A, 0);
    k_copy4<<<(NN * DD / 4 + 255) / 256, 256, 0, stream>>>((const float4*)A, (float4*)B, NN * DD / 4);
}

// Round 4
// 460.521 us; speedup vs baseline: 1.8012x; 1.0174x over previous
//
#include <hip/hip_runtime.h>

#define NN 100000
#define NE 1200000
#define DD 64
#define NPART 8
#define PSZ (NN / NPART)                        // 12500
#define EPB 4096                                // edges per block-chunk in partitioned scatter
#define NCHUNK ((NE + EPB - 1) / EPB)           // 293
#define SCAN_CH 256
#define SCAN_T ((NN + SCAN_CH - 1) / SCAN_CH)   // 391

// bf16 helpers (round-to-nearest-even)
static __device__ __forceinline__ unsigned short f2bf(float f) {
    unsigned int u = __float_as_uint(f);
    u += 0x7fffu + ((u >> 16) & 1u);
    return (unsigned short)(u >> 16);
}
static __device__ __forceinline__ float bf2f(unsigned short h) {
    return __uint_as_float(((unsigned int)h) << 16);
}

// ---------------- dst-partitioned histogram ----------------
// block b: edge chunk b>>3, dst partition b&7. Atomics land in a 50KB
// partition-local window (XCD-local L2 under blockIdx%8 round-robin).
__global__ __launch_bounds__(256) void k_hist(const int* __restrict__ dst,
                                              int* __restrict__ degi, int ne) {
    int part = blockIdx.x & (NPART - 1);
    int lo = part * PSZ, hi = lo + PSZ;
    int beg = (blockIdx.x >> 3) * EPB;
    int end = min(beg + EPB, ne);
    for (int e = beg + (int)threadIdx.x; e < end; e += 256) {
        int d = dst[e];
        if (d >= lo && d < hi) atomicAdd(&degi[d], 1);
    }
}

__global__ void k_dinv(const int* __restrict__ degi, float* __restrict__ dinv, int n) {
    int i = blockIdx.x * blockDim.x + threadIdx.x;
    if (i < n) dinv[i] = rsqrtf((float)degi[i] + 1.0f);
}

// ---------------- exclusive scan (3 kernels) ----------------
__global__ void k_scan1(const int* __restrict__ degi, int* __restrict__ partial) {
    int t = blockIdx.x * blockDim.x + threadIdx.x;
    if (t >= SCAN_T) return;
    int beg = t * SCAN_CH, end = min(beg + SCAN_CH, NN);
    int s = 0;
    for (int i = beg; i < end; ++i) s += degi[i];
    partial[t] = s;
}

__global__ __launch_bounds__(512) void k_scan2(int* __restrict__ partial, int* __restrict__ rowptr) {
    __shared__ int sm[512];
    int t = threadIdx.x;
    int v = (t < SCAN_T) ? partial[t] : 0;
    sm[t] = v;
    __syncthreads();
    for (int off = 1; off < 512; off <<= 1) {
        int add = (t >= off) ? sm[t - off] : 0;
        __syncthreads();
        sm[t] += add;
        __syncthreads();
    }
    if (t < SCAN_T) partial[t] = sm[t] - v;   // exclusive
    if (t == 0) rowptr[NN] = NE;
}

__global__ void k_scan3(const int* __restrict__ degi, const int* __restrict__ partial,
                        int* __restrict__ rowptr) {
    int t = blockIdx.x * blockDim.x + threadIdx.x;
    if (t >= SCAN_T) return;
    int beg = t * SCAN_CH, end = min(beg + SCAN_CH, NN);
    int run = partial[t];
    for (int i = beg; i < end; ++i) { rowptr[i] = run; run += degi[i]; }
}

// ---------------- dst-partitioned CSR fill ----------------
// Partition p's csr window is contiguous (CSR is node-ordered): full-line,
// L2-local write-back instead of 1 HBM line per 4B store.
__global__ __launch_bounds__(256) void k_fill(const int* __restrict__ src,
                                              const int* __restrict__ dst,
                                              const int* __restrict__ rowptr,
                                              int* __restrict__ cnt,
                                              int* __restrict__ csr_src, int ne) {
    int part = blockIdx.x & (NPART - 1);
    int lo = part * PSZ, hi = lo + PSZ;
    int beg = (blockIdx.x >> 3) * EPB;
    int end = min(beg + EPB, ne);
    for (int e = beg + (int)threadIdx.x; e < end; e += 256) {
        int d = dst[e];
        if (d >= lo && d < hi) {
            int pos = rowptr[d] + atomicAdd(&cnt[d], 1);
            csr_src[pos] = src[e];
        }
    }
}

// ---------------- GEMM: Hb_bf16[n,64] = X[n,64] @ W[64,64] ----------------
__global__ __launch_bounds__(256) void k_gemm_bf(const float* __restrict__ X,
                                                 const float* __restrict__ W,
                                                 unsigned short* __restrict__ Hb,
                                                 int nrows) {
    __shared__ float4 Ws4[64][16];      // 16 KB: W[k][c4]
    __shared__ float  Xs[64][68];       // padded stride
    int tid = threadIdx.x;
    const float4* W4 = (const float4*)W;
    for (int i = tid; i < 64 * 16; i += 256) Ws4[i >> 4][i & 15] = W4[i];
    int row0 = blockIdx.x * 64;
    const float4* X4 = (const float4*)X;
    for (int i = tid; i < 64 * 16; i += 256) {
        int r = i >> 4, q = i & 15;
        int row = row0 + r;
        float4 v = make_float4(0.f, 0.f, 0.f, 0.f);
        if (row < nrows) v = X4[row * 16 + q];
        *((float4*)&Xs[r][q * 4]) = v;
    }
    __syncthreads();
    int c4 = tid & 15;
    int rg = tid >> 4;
    float4 acc0 = make_float4(0.f, 0.f, 0.f, 0.f);
    float4 acc1 = acc0, acc2 = acc0, acc3 = acc0;
#pragma unroll 4
    for (int k = 0; k < 64; ++k) {
        float4 w = Ws4[k][c4];
        float x0 = Xs[rg * 4 + 0][k];
        float x1 = Xs[rg * 4 + 1][k];
        float x2 = Xs[rg * 4 + 2][k];
        float x3 = Xs[rg * 4 + 3][k];
        acc0.x += x0 * w.x; acc0.y += x0 * w.y; acc0.z += x0 * w.z; acc0.w += x0 * w.w;
        acc1.x += x1 * w.x; acc1.y += x1 * w.y; acc1.z += x1 * w.z; acc1.w += x1 * w.w;
        acc2.x += x2 * w.x; acc2.y += x2 * w.y; acc2.z += x2 * w.z; acc2.w += x2 * w.w;
        acc3.x += x3 * w.x; acc3.y += x3 * w.y; acc3.z += x3 * w.z; acc3.w += x3 * w.w;
    }
    float4 accs[4] = {acc0, acc1, acc2, acc3};
#pragma unroll
    for (int i = 0; i < 4; ++i) {
        int row = row0 + rg * 4 + i;
        if (row < nrows) {
            ushort4 o;
            o.x = f2bf(accs[i].x); o.y = f2bf(accs[i].y);
            o.z = f2bf(accs[i].z); o.w = f2bf(accs[i].w);
            *((ushort4*)&Hb[row * 64 + c4 * 4]) = o;
        }
    }
}

// ---------------- fused gather-reduce + self-loop + bias (+relu) ----------------
__global__ __launch_bounds__(256) void k_reduce(const unsigned short* __restrict__ Hb,
                                                const int* __restrict__ rowptr,
                                                const int* __restrict__ csr_src,
                                                const float* __restrict__ dinv,
                                                const float* __restrict__ b,
                                                float* __restrict__ out0,
                                                float* __restrict__ out1,
                                                int do_relu) {
    int n = blockIdx.x * 4 + (threadIdx.x >> 6);
    if (n >= NN) return;
    int c = threadIdx.x & 63;
    float din = dinv[n];
    float acc = bf2f(Hb[n * 64 + c]) * din * din;     // self loop
    int e = rowptr[n], end = rowptr[n + 1];
    for (; e + 3 < end; e += 4) {
        int s0 = csr_src[e], s1 = csr_src[e + 1], s2 = csr_src[e + 2], s3 = csr_src[e + 3];
        float v0 = bf2f(Hb[s0 * 64 + c]);
        float v1 = bf2f(Hb[s1 * 64 + c]);
        float v2 = bf2f(Hb[s2 * 64 + c]);
        float v3 = bf2f(Hb[s3 * 64 + c]);
        float c0 = dinv[s0] * din, c1 = dinv[s1] * din;
        float c2 = dinv[s2] * din, c3 = dinv[s3] * din;
        acc += v0 * c0; acc += v1 * c1; acc += v2 * c2; acc += v3 * c3;
    }
    for (; e < end; ++e) {
        int s0 = csr_src[e];
        acc += bf2f(Hb[s0 * 64 + c]) * (dinv[s0] * din);
    }
    float v = acc + b[c];
    if (do_relu) v = fmaxf(v, 0.f);
    out0[n * 64 + c] = v;
    if (out1) out1[n * 64 + c] = v;
}

__global__ void k_copy4(const float4* __restrict__ in, float4* __restrict__ out, int n4) {
    int i = blockIdx.x * blockDim.x + threadIdx.x;
    if (i < n4) out[i] = in[i];
}

extern "C" void kernel_launch(void* const* d_in, const int* in_sizes, int n_in,
                              void* d_out, int out_size, void* d_ws, size_t ws_size,
                              hipStream_t stream) {
    const float* x  = (const float*)d_in[0];
    const int*   ei = (const int*)d_in[1];     // [2, NE]: src row then dst row
    const float* W1 = (const float*)d_in[2];
    const float* b1 = (const float*)d_in[3];
    const float* W2 = (const float*)d_in[4];
    const float* b2 = (const float*)d_in[5];
    const int* src = ei;
    const int* dst = ei + NE;

    float* A = (float*)d_out;                   // half 0: final h
    float* B = (float*)d_out + (size_t)NN * DD; // half 1: final h

    // ws layout
    char* w = (char*)d_ws;
    size_t off = 0;
    auto alloc = [&](size_t bytes) { void* p = w + off; off += (bytes + 255) & ~(size_t)255; return p; };
    float* dinv   = (float*)alloc(NN * sizeof(float));
    int*   degi   = (int*)  alloc(NN * sizeof(int));
    int*   cnt    = (int*)  alloc(NN * sizeof(int));
    int*   rowptr = (int*)  alloc((NN + 1) * sizeof(int));
    int*   part   = (int*)  alloc(512 * sizeof(int));
    int*   csr    = (int*)  alloc(NE * sizeof(int));
    size_t base = off;
    unsigned short* Bb_ws = (unsigned short*)alloc((size_t)NN * DD * sizeof(unsigned short));
    bool big_ws = (ws_size >= base + (size_t)NN * DD * sizeof(unsigned short));
    unsigned short* Bb = big_ws ? Bb_ws : (unsigned short*)B;

    int grid_part = NCHUNK * NPART;

    // ---- CSR build ----
    hipMemsetAsync(degi, 0, NN * sizeof(int), stream);
    hipMemsetAsync(cnt, 0, NN * sizeof(int), stream);
    k_hist<<<grid_part, 256, 0, stream>>>(dst, degi, NE);
    k_dinv<<<(NN + 255) / 256, 256, 0, stream>>>(degi, dinv, NN);
    k_scan1<<<(SCAN_T + 255) / 256, 256, 0, stream>>>(degi, part);
    k_scan2<<<1, 512, 0, stream>>>(part, rowptr);
    k_scan3<<<(SCAN_T + 255) / 256, 256, 0, stream>>>(degi, part, rowptr);
    k_fill<<<grid_part, 256, 0, stream>>>(src, dst, rowptr, cnt, csr, NE);

    // ---- layer 1: Bb = bf16(x@W1); A = relu(agg(Bb)+b1) ----
    k_gemm_bf<<<(NN + 63) / 64, 256, 0, stream>>>(x, W1, Bb, NN);
    k_reduce<<<(NN + 3) / 4, 256, 0, stream>>>(Bb, rowptr, csr, dinv, b1, A, nullptr, 1);

    // ---- layer 2: Bb = bf16(A@W2); out = agg(Bb)+b2 ----
    k_gemm_bf<<<(NN + 63) / 64, 256, 0, stream>>>(A, W2, Bb, NN);
    if (big_ws) {
        // Bb in ws: reduce can write both output halves directly (no overlap)
        k_reduce<<<(NN + 3) / 4, 256, 0, stream>>>(Bb, rowptr, csr, dinv, b2, A, B, 0);
    } else {
        k_reduce<<<(NN + 3) / 4, 256, 0, stream>>>(Bb, rowptr, csr, dinv, b2, A, nullptr, 0);
        k_copy4<<<(NN * DD / 4 + 255) / 256, 256, 0, stream>>>((const float4*)A, (float4*)B, NN * DD / 4);
    }
}

// Round 5
// 363.596 us; speedup vs baseline: 2.2813x; 1.2666x over previous
//
#include <hip/hip_runtime.h>

#define NN 100000
#define NE 1200000
#define DD 64
#define NPART 8
#define PSZ (NN / NPART)                        // 12500
#define EPB 4096                                // edges per block-chunk in partitioned scatter
#define NCHUNK ((NE + EPB - 1) / EPB)           // 293
#define SCH 1024                                // scan chunk (elements per block)
#define SNB ((NN + SCH - 1) / SCH)              // 98 scan blocks

// bf16 helpers (round-to-nearest-even)
static __device__ __forceinline__ unsigned short f2bf(float f) {
    unsigned int u = __float_as_uint(f);
    u += 0x7fffu + ((u >> 16) & 1u);
    return (unsigned short)(u >> 16);
}
static __device__ __forceinline__ float bf2f(unsigned short h) {
    return __uint_as_float(((unsigned int)h) << 16);
}

// ---------------- dst-partitioned histogram ----------------
__global__ __launch_bounds__(256) void k_hist(const int* __restrict__ dst,
                                              int* __restrict__ degi, int ne) {
    int part = blockIdx.x & (NPART - 1);
    int lo = part * PSZ, hi = lo + PSZ;
    int beg = (blockIdx.x >> 3) * EPB;
    int end = min(beg + EPB, ne);
    for (int e = beg + (int)threadIdx.x; e < end; e += 256) {
        int d = dst[e];
        if (d >= lo && d < hi) atomicAdd(&degi[d], 1);
    }
}

__global__ void k_dinv(const int* __restrict__ degi, float* __restrict__ dinv, int n) {
    int i = blockIdx.x * blockDim.x + threadIdx.x;
    if (i < n) dinv[i] = rsqrtf((float)degi[i] + 1.0f);
}

// ---------------- parallel exclusive scan, phase 1 ----------------
// 98 blocks x 256 thr x 4 elem: wave shfl-scan + LDS wave-offset combine.
// Writes block-local exclusive prefixes into rowptr, chunk totals into part.
__global__ __launch_bounds__(256) void k_scan_local(const int* __restrict__ degi,
                                                    int* __restrict__ rowptr,
                                                    int* __restrict__ part) {
    __shared__ int wsum[4];
    int t = threadIdx.x;
    int idx = blockIdx.x * SCH + t * 4;
    int d0 = 0, d1 = 0, d2 = 0, d3 = 0;
    if (idx + 3 < NN) {
        int4 v = *(const int4*)&degi[idx];
        d0 = v.x; d1 = v.y; d2 = v.z; d3 = v.w;
    } else {
        if (idx     < NN) d0 = degi[idx];
        if (idx + 1 < NN) d1 = degi[idx + 1];
        if (idx + 2 < NN) d2 = degi[idx + 2];
        if (idx + 3 < NN) d3 = degi[idx + 3];
    }
    int s = d0 + d1 + d2 + d3;
    int lane = t & 63;
    int incl = s;
#pragma unroll
    for (int off = 1; off < 64; off <<= 1) {
        int v = __shfl_up(incl, off);
        if (lane >= off) incl += v;
    }
    int wv = t >> 6;
    if (lane == 63) wsum[wv] = incl;
    __syncthreads();
    int woff = 0;
#pragma unroll
    for (int i = 0; i < 4; ++i) if (i < wv) woff += wsum[i];
    int excl = woff + incl - s;
    if (idx     < NN) rowptr[idx]     = excl;
    if (idx + 1 < NN) rowptr[idx + 1] = excl + d0;
    if (idx + 2 < NN) rowptr[idx + 2] = excl + d0 + d1;
    if (idx + 3 < NN) rowptr[idx + 3] = excl + d0 + d1 + d2;
    if (t == 255) part[blockIdx.x] = woff + incl;   // chunk total
}

// phase 2: exclusive scan of the 98 chunk totals (single small block)
__global__ __launch_bounds__(128) void k_scan_part(int* __restrict__ part) {
    __shared__ int sm[128];
    int t = threadIdx.x;
    int v = (t < SNB) ? part[t] : 0;
    sm[t] = v;
    __syncthreads();
    for (int off = 1; off < 128; off <<= 1) {
        int add = (t >= off) ? sm[t - off] : 0;
        __syncthreads();
        sm[t] += add;
        __syncthreads();
    }
    if (t < SNB) part[t] = sm[t] - v;   // exclusive
}

// phase 3: add chunk offsets
__global__ void k_scan_add(int* __restrict__ rowptr, const int* __restrict__ part) {
    int i = blockIdx.x * blockDim.x + threadIdx.x;
    if (i < NN) rowptr[i] += part[i >> 10];
    if (i == 0) rowptr[NN] = NE;
}

// ---------------- dst-partitioned CSR fill ----------------
__global__ __launch_bounds__(256) void k_fill(const int* __restrict__ src,
                                              const int* __restrict__ dst,
                                              const int* __restrict__ rowptr,
                                              int* __restrict__ cnt,
                                              int* __restrict__ csr_src, int ne) {
    int part = blockIdx.x & (NPART - 1);
    int lo = part * PSZ, hi = lo + PSZ;
    int beg = (blockIdx.x >> 3) * EPB;
    int end = min(beg + EPB, ne);
    for (int e = beg + (int)threadIdx.x; e < end; e += 256) {
        int d = dst[e];
        if (d >= lo && d < hi) {
            int pos = rowptr[d] + atomicAdd(&cnt[d], 1);
            csr_src[pos] = src[e];
        }
    }
}

// ---------------- GEMM: Hb_bf16[n,64] = X[n,64] @ W[64,64] ----------------
__global__ __launch_bounds__(256) void k_gemm_bf(const float* __restrict__ X,
                                                 const float* __restrict__ W,
                                                 unsigned short* __restrict__ Hb,
                                                 int nrows) {
    __shared__ float4 Ws4[64][16];      // 16 KB: W[k][c4]
    __shared__ float  Xs[64][68];       // padded stride
    int tid = threadIdx.x;
    const float4* W4 = (const float4*)W;
    for (int i = tid; i < 64 * 16; i += 256) Ws4[i >> 4][i & 15] = W4[i];
    int row0 = blockIdx.x * 64;
    const float4* X4 = (const float4*)X;
    for (int i = tid; i < 64 * 16; i += 256) {
        int r = i >> 4, q = i & 15;
        int row = row0 + r;
        float4 v = make_float4(0.f, 0.f, 0.f, 0.f);
        if (row < nrows) v = X4[row * 16 + q];
        *((float4*)&Xs[r][q * 4]) = v;
    }
    __syncthreads();
    int c4 = tid & 15;
    int rg = tid >> 4;
    float4 acc0 = make_float4(0.f, 0.f, 0.f, 0.f);
    float4 acc1 = acc0, acc2 = acc0, acc3 = acc0;
#pragma unroll 4
    for (int k = 0; k < 64; ++k) {
        float4 w = Ws4[k][c4];
        float x0 = Xs[rg * 4 + 0][k];
        float x1 = Xs[rg * 4 + 1][k];
        float x2 = Xs[rg * 4 + 2][k];
        float x3 = Xs[rg * 4 + 3][k];
        acc0.x += x0 * w.x; acc0.y += x0 * w.y; acc0.z += x0 * w.z; acc0.w += x0 * w.w;
        acc1.x += x1 * w.x; acc1.y += x1 * w.y; acc1.z += x1 * w.z; acc1.w += x1 * w.w;
        acc2.x += x2 * w.x; acc2.y += x2 * w.y; acc2.z += x2 * w.z; acc2.w += x2 * w.w;
        acc3.x += x3 * w.x; acc3.y += x3 * w.y; acc3.z += x3 * w.z; acc3.w += x3 * w.w;
    }
    float4 accs[4] = {acc0, acc1, acc2, acc3};
#pragma unroll
    for (int i = 0; i < 4; ++i) {
        int row = row0 + rg * 4 + i;
        if (row < nrows) {
            ushort4 o;
            o.x = f2bf(accs[i].x); o.y = f2bf(accs[i].y);
            o.z = f2bf(accs[i].z); o.w = f2bf(accs[i].w);
            *((ushort4*)&Hb[row * 64 + c4 * 4]) = o;
        }
    }
}

// ---------------- fused gather-reduce + self-loop + bias (+relu) ----------------
__global__ __launch_bounds__(256) void k_reduce(const unsigned short* __restrict__ Hb,
                                                const int* __restrict__ rowptr,
                                                const int* __restrict__ csr_src,
                                                const float* __restrict__ dinv,
                                                const float* __restrict__ b,
                                                float* __restrict__ out0,
                                                float* __restrict__ out1,
                                                int do_relu) {
    int n = blockIdx.x * 4 + (threadIdx.x >> 6);
    if (n >= NN) return;
    int c = threadIdx.x & 63;
    float din = dinv[n];
    float acc = bf2f(Hb[n * 64 + c]) * din * din;     // self loop
    int e = rowptr[n], end = rowptr[n + 1];
    for (; e + 3 < end; e += 4) {
        int s0 = csr_src[e], s1 = csr_src[e + 1], s2 = csr_src[e + 2], s3 = csr_src[e + 3];
        float v0 = bf2f(Hb[s0 * 64 + c]);
        float v1 = bf2f(Hb[s1 * 64 + c]);
        float v2 = bf2f(Hb[s2 * 64 + c]);
        float v3 = bf2f(Hb[s3 * 64 + c]);
        float c0 = dinv[s0] * din, c1 = dinv[s1] * din;
        float c2 = dinv[s2] * din, c3 = dinv[s3] * din;
        acc += v0 * c0; acc += v1 * c1; acc += v2 * c2; acc += v3 * c3;
    }
    for (; e < end; ++e) {
        int s0 = csr_src[e];
        acc += bf2f(Hb[s0 * 64 + c]) * (dinv[s0] * din);
    }
    float v = acc + b[c];
    if (do_relu) v = fmaxf(v, 0.f);
    out0[n * 64 + c] = v;
    if (out1) out1[n * 64 + c] = v;
}

__global__ void k_copy4(const float4* __restrict__ in, float4* __restrict__ out, int n4) {
    int i = blockIdx.x * blockDim.x + threadIdx.x;
    if (i < n4) out[i] = in[i];
}

extern "C" void kernel_launch(void* const* d_in, const int* in_sizes, int n_in,
                              void* d_out, int out_size, void* d_ws, size_t ws_size,
                              hipStream_t stream) {
    const float* x  = (const float*)d_in[0];
    const int*   ei = (const int*)d_in[1];     // [2, NE]: src row then dst row
    const float* W1 = (const float*)d_in[2];
    const float* b1 = (const float*)d_in[3];
    const float* W2 = (const float*)d_in[4];
    const float* b2 = (const float*)d_in[5];
    const int* src = ei;
    const int* dst = ei + NE;

    float* A = (float*)d_out;                   // half 0: final h
    float* B = (float*)d_out + (size_t)NN * DD; // half 1: final h

    // ws layout
    char* w = (char*)d_ws;
    size_t off = 0;
    auto alloc = [&](size_t bytes) { void* p = w + off; off += (bytes + 255) & ~(size_t)255; return p; };
    float* dinv   = (float*)alloc(NN * sizeof(float));
    int*   degi   = (int*)  alloc(NN * sizeof(int));
    int*   cnt    = (int*)  alloc(NN * sizeof(int));
    int*   rowptr = (int*)  alloc((NN + 1) * sizeof(int));
    int*   part   = (int*)  alloc(512 * sizeof(int));
    int*   csr    = (int*)  alloc(NE * sizeof(int));
    size_t base = off;
    unsigned short* Bb_ws = (unsigned short*)alloc((size_t)NN * DD * sizeof(unsigned short));
    bool big_ws = (ws_size >= base + (size_t)NN * DD * sizeof(unsigned short));
    unsigned short* Bb = big_ws ? Bb_ws : (unsigned short*)B;

    int grid_part = NCHUNK * NPART;

    // ---- CSR build ----
    hipMemsetAsync(degi, 0, NN * sizeof(int), stream);
    hipMemsetAsync(cnt, 0, NN * sizeof(int), stream);
    k_hist<<<grid_part, 256, 0, stream>>>(dst, degi, NE);
    k_dinv<<<(NN + 255) / 256, 256, 0, stream>>>(degi, dinv, NN);
    k_scan_local<<<SNB, 256, 0, stream>>>(degi, rowptr, part);
    k_scan_part<<<1, 128, 0, stream>>>(part);
    k_scan_add<<<(NN + 255) / 256, 256, 0, stream>>>(rowptr, part);
    k_fill<<<grid_part, 256, 0, stream>>>(src, dst, rowptr, cnt, csr, NE);

    // ---- layer 1: Bb = bf16(x@W1); A = relu(agg(Bb)+b1) ----
    k_gemm_bf<<<(NN + 63) / 64, 256, 0, stream>>>(x, W1, Bb, NN);
    k_reduce<<<(NN + 3) / 4, 256, 0, stream>>>(Bb, rowptr, csr, dinv, b1, A, nullptr, 1);

    // ---- layer 2: Bb = bf16(A@W2); out = agg(Bb)+b2 ----
    k_gemm_bf<<<(NN + 63) / 64, 256, 0, stream>>>(A, W2, Bb, NN);
    if (big_ws) {
        k_reduce<<<(NN + 3) / 4, 256, 0, stream>>>(Bb, rowptr, csr, dinv, b2, A, B, 0);
    } else {
        k_reduce<<<(NN + 3) / 4, 256, 0, stream>>>(Bb, rowptr, csr, dinv, b2, A, nullptr, 0);
        k_copy4<<<(NN * DD / 4 + 255) / 256, 256, 0, stream>>>((const float4*)A, (float4*)B, NN * DD / 4);
    }
}

// Round 6
// 327.330 us; speedup vs baseline: 2.5341x; 1.1108x over previous
//
#include <hip/hip_runtime.h>

#define NN 100000
#define NE 1200000
#define DD 64
#define NPART 8
#define PSZ (NN / NPART)                        // 12500
#define EPB 4096
#define NCHUNK ((NE + EPB - 1) / EPB)           // 293
#define SCH 1024                                // scan chunk (elements per block)
#define SNB ((NN + SCH - 1) / SCH)              // 98 scan blocks

// bf16 helpers (round-to-nearest-even)
static __device__ __forceinline__ unsigned short f2bf(float f) {
    unsigned int u = __float_as_uint(f);
    u += 0x7fffu + ((u >> 16) & 1u);
    return (unsigned short)(u >> 16);
}
static __device__ __forceinline__ float bf2f(unsigned short h) {
    return __uint_as_float(((unsigned int)h) << 16);
}

// ---------------- histogram + rank (atomic return value = rank in dst segment) ----------------
__global__ void k_hist_rank(const int* __restrict__ dst, int* __restrict__ degi,
                            int* __restrict__ rank, int ne) {
    int i = blockIdx.x * blockDim.x + threadIdx.x;
    if (i < ne) rank[i] = atomicAdd(&degi[dst[i]], 1);
}

// fallback partitioned histogram (no rank buffer)
__global__ __launch_bounds__(256) void k_hist(const int* __restrict__ dst,
                                              int* __restrict__ degi, int ne) {
    int part = blockIdx.x & (NPART - 1);
    int lo = part * PSZ, hi = lo + PSZ;
    int beg = (blockIdx.x >> 3) * EPB;
    int end = min(beg + EPB, ne);
    for (int e = beg + (int)threadIdx.x; e < end; e += 256) {
        int d = dst[e];
        if (d >= lo && d < hi) atomicAdd(&degi[d], 1);
    }
}

__global__ void k_dinv(const int* __restrict__ degi, float* __restrict__ dinv, int n) {
    int i = blockIdx.x * blockDim.x + threadIdx.x;
    if (i < n) dinv[i] = rsqrtf((float)degi[i] + 1.0f);
}

// ---------------- parallel exclusive scan ----------------
__global__ __launch_bounds__(256) void k_scan_local(const int* __restrict__ degi,
                                                    int* __restrict__ rowptr,
                                                    int* __restrict__ part) {
    __shared__ int wsum[4];
    int t = threadIdx.x;
    int idx = blockIdx.x * SCH + t * 4;
    int d0 = 0, d1 = 0, d2 = 0, d3 = 0;
    if (idx + 3 < NN) {
        int4 v = *(const int4*)&degi[idx];
        d0 = v.x; d1 = v.y; d2 = v.z; d3 = v.w;
    } else {
        if (idx     < NN) d0 = degi[idx];
        if (idx + 1 < NN) d1 = degi[idx + 1];
        if (idx + 2 < NN) d2 = degi[idx + 2];
        if (idx + 3 < NN) d3 = degi[idx + 3];
    }
    int s = d0 + d1 + d2 + d3;
    int lane = t & 63;
    int incl = s;
#pragma unroll
    for (int off = 1; off < 64; off <<= 1) {
        int v = __shfl_up(incl, off);
        if (lane >= off) incl += v;
    }
    int wv = t >> 6;
    if (lane == 63) wsum[wv] = incl;
    __syncthreads();
    int woff = 0;
#pragma unroll
    for (int i = 0; i < 4; ++i) if (i < wv) woff += wsum[i];
    int excl = woff + incl - s;
    if (idx     < NN) rowptr[idx]     = excl;
    if (idx + 1 < NN) rowptr[idx + 1] = excl + d0;
    if (idx + 2 < NN) rowptr[idx + 2] = excl + d0 + d1;
    if (idx + 3 < NN) rowptr[idx + 3] = excl + d0 + d1 + d2;
    if (t == 255) part[blockIdx.x] = woff + incl;
}

__global__ __launch_bounds__(128) void k_scan_part(int* __restrict__ part) {
    __shared__ int sm[128];
    int t = threadIdx.x;
    int v = (t < SNB) ? part[t] : 0;
    sm[t] = v;
    __syncthreads();
    for (int off = 1; off < 128; off <<= 1) {
        int add = (t >= off) ? sm[t - off] : 0;
        __syncthreads();
        sm[t] += add;
        __syncthreads();
    }
    if (t < SNB) part[t] = sm[t] - v;
}

__global__ void k_scan_add(int* __restrict__ rowptr, const int* __restrict__ part) {
    int i = blockIdx.x * blockDim.x + threadIdx.x;
    if (i < NN) rowptr[i] += part[i >> 10];
    if (i == 0) rowptr[NN] = NE;
}

// ---------------- atomic-free CSR fill using precomputed ranks ----------------
__global__ void k_fill_rank(const int* __restrict__ src, const int* __restrict__ dst,
                            const int* __restrict__ rank, const int* __restrict__ rowptr,
                            int* __restrict__ csr_src, int ne) {
    int e = blockIdx.x * blockDim.x + threadIdx.x;
    if (e < ne) csr_src[rowptr[dst[e]] + rank[e]] = src[e];
}

// fallback partitioned fill with cursor atomics
__global__ __launch_bounds__(256) void k_fill(const int* __restrict__ src,
                                              const int* __restrict__ dst,
                                              const int* __restrict__ rowptr,
                                              int* __restrict__ cnt,
                                              int* __restrict__ csr_src, int ne) {
    int part = blockIdx.x & (NPART - 1);
    int lo = part * PSZ, hi = lo + PSZ;
    int beg = (blockIdx.x >> 3) * EPB;
    int end = min(beg + EPB, ne);
    for (int e = beg + (int)threadIdx.x; e < end; e += 256) {
        int d = dst[e];
        if (d >= lo && d < hi) {
            int pos = rowptr[d] + atomicAdd(&cnt[d], 1);
            csr_src[pos] = src[e];
        }
    }
}

// ---------------- GEMM: Hb_bf16[n,64] = X[n,64] @ W[64,64] ----------------
__global__ __launch_bounds__(256) void k_gemm_bf(const float* __restrict__ X,
                                                 const float* __restrict__ W,
                                                 unsigned short* __restrict__ Hb,
                                                 int nrows) {
    __shared__ float4 Ws4[64][16];
    __shared__ float  Xs[64][68];
    int tid = threadIdx.x;
    const float4* W4 = (const float4*)W;
    for (int i = tid; i < 64 * 16; i += 256) Ws4[i >> 4][i & 15] = W4[i];
    int row0 = blockIdx.x * 64;
    const float4* X4 = (const float4*)X;
    for (int i = tid; i < 64 * 16; i += 256) {
        int r = i >> 4, q = i & 15;
        int row = row0 + r;
        float4 v = make_float4(0.f, 0.f, 0.f, 0.f);
        if (row < nrows) v = X4[row * 16 + q];
        *((float4*)&Xs[r][q * 4]) = v;
    }
    __syncthreads();
    int c4 = tid & 15;
    int rg = tid >> 4;
    float4 acc0 = make_float4(0.f, 0.f, 0.f, 0.f);
    float4 acc1 = acc0, acc2 = acc0, acc3 = acc0;
#pragma unroll 4
    for (int k = 0; k < 64; ++k) {
        float4 w = Ws4[k][c4];
        float x0 = Xs[rg * 4 + 0][k];
        float x1 = Xs[rg * 4 + 1][k];
        float x2 = Xs[rg * 4 + 2][k];
        float x3 = Xs[rg * 4 + 3][k];
        acc0.x += x0 * w.x; acc0.y += x0 * w.y; acc0.z += x0 * w.z; acc0.w += x0 * w.w;
        acc1.x += x1 * w.x; acc1.y += x1 * w.y; acc1.z += x1 * w.z; acc1.w += x1 * w.w;
        acc2.x += x2 * w.x; acc2.y += x2 * w.y; acc2.z += x2 * w.z; acc2.w += x2 * w.w;
        acc3.x += x3 * w.x; acc3.y += x3 * w.y; acc3.z += x3 * w.z; acc3.w += x3 * w.w;
    }
    float4 accs[4] = {acc0, acc1, acc2, acc3};
#pragma unroll
    for (int i = 0; i < 4; ++i) {
        int row = row0 + rg * 4 + i;
        if (row < nrows) {
            ushort4 o;
            o.x = f2bf(accs[i].x); o.y = f2bf(accs[i].y);
            o.z = f2bf(accs[i].z); o.w = f2bf(accs[i].w);
            *((ushort4*)&Hb[row * 64 + c4 * 4]) = o;
        }
    }
}

// ---------------- pair-gather fused reduce ----------------
// Wave = 1 dst node. half = lane>>5 picks edge parity; c2 = lane&31 picks col pair.
// Each gather instruction moves 2 x 128B rows; halves combined via shfl_xor(32).
__global__ __launch_bounds__(256) void k_reduce(const unsigned short* __restrict__ Hb,
                                                const int* __restrict__ rowptr,
                                                const int* __restrict__ csr_src,
                                                const float* __restrict__ dinv,
                                                const float* __restrict__ b,
                                                float* __restrict__ out0,
                                                float* __restrict__ out1,
                                                int do_relu) {
    int n = blockIdx.x * 4 + (threadIdx.x >> 6);
    if (n >= NN) return;
    int lane = threadIdx.x & 63;
    int half = lane >> 5;
    int c2 = lane & 31;
    float din = dinv[n];
    float ax = 0.f, ay = 0.f;
    int e = rowptr[n], end = rowptr[n + 1];
    for (; e + 3 < end; e += 4) {
        int sA = csr_src[e + half];
        int sB = csr_src[e + 2 + half];
        float cA = dinv[sA] * din;
        float cB = dinv[sB] * din;
        unsigned int uA = *(const unsigned int*)&Hb[sA * 64 + c2 * 2];
        unsigned int uB = *(const unsigned int*)&Hb[sB * 64 + c2 * 2];
        ax += bf2f((unsigned short)uA) * cA;
        ay += bf2f((unsigned short)(uA >> 16)) * cA;
        ax += bf2f((unsigned short)uB) * cB;
        ay += bf2f((unsigned short)(uB >> 16)) * cB;
    }
    for (; e < end; e += 2) {
        int idx = e + half;
        bool v = idx < end;
        int s = v ? csr_src[idx] : 0;
        float cf = v ? dinv[s] * din : 0.f;
        unsigned int u = *(const unsigned int*)&Hb[s * 64 + c2 * 2];
        ax += bf2f((unsigned short)u) * cf;
        ay += bf2f((unsigned short)(u >> 16)) * cf;
    }
    ax += __shfl_xor(ax, 32);
    ay += __shfl_xor(ay, 32);
    if (half == 0) {
        unsigned int us = *(const unsigned int*)&Hb[n * 64 + c2 * 2];
        float dd = din * din;
        float vx = ax + bf2f((unsigned short)us) * dd + b[c2 * 2];
        float vy = ay + bf2f((unsigned short)(us >> 16)) * dd + b[c2 * 2 + 1];
        if (do_relu) { vx = fmaxf(vx, 0.f); vy = fmaxf(vy, 0.f); }
        float2 o = make_float2(vx, vy);
        *(float2*)&out0[n * 64 + c2 * 2] = o;
        if (out1) *(float2*)&out1[n * 64 + c2 * 2] = o;
    }
}

__global__ void k_copy4(const float4* __restrict__ in, float4* __restrict__ out, int n4) {
    int i = blockIdx.x * blockDim.x + threadIdx.x;
    if (i < n4) out[i] = in[i];
}

extern "C" void kernel_launch(void* const* d_in, const int* in_sizes, int n_in,
                              void* d_out, int out_size, void* d_ws, size_t ws_size,
                              hipStream_t stream) {
    const float* x  = (const float*)d_in[0];
    const int*   ei = (const int*)d_in[1];     // [2, NE]: src row then dst row
    const float* W1 = (const float*)d_in[2];
    const float* b1 = (const float*)d_in[3];
    const float* W2 = (const float*)d_in[4];
    const float* b2 = (const float*)d_in[5];
    const int* src = ei;
    const int* dst = ei + NE;

    float* A = (float*)d_out;                   // half 0: final h
    float* B = (float*)d_out + (size_t)NN * DD; // half 1: final h

    // ws layout
    char* w = (char*)d_ws;
    size_t off = 0;
    auto alloc = [&](size_t bytes) { void* p = w + off; off += (bytes + 255) & ~(size_t)255; return p; };
    float* dinv   = (float*)alloc(NN * sizeof(float));
    int*   degi   = (int*)  alloc(NN * sizeof(int));
    int*   cnt    = (int*)  alloc(NN * sizeof(int));
    int*   rowptr = (int*)  alloc((NN + 1) * sizeof(int));
    int*   part   = (int*)  alloc(512 * sizeof(int));
    int*   csr    = (int*)  alloc(NE * sizeof(int));
    size_t off_base = off;
    int*   rank   = (int*)  alloc(NE * sizeof(int));
    size_t off_rank = off;
    unsigned short* Bb_ws = (unsigned short*)alloc((size_t)NN * DD * sizeof(unsigned short));
    size_t off_bb = off;
    bool has_rank = (ws_size >= off_rank);
    bool big_ws   = (ws_size >= off_bb);
    unsigned short* Bb = big_ws ? Bb_ws : (unsigned short*)B;
    (void)off_base;

    // ---- CSR build ----
    hipMemsetAsync(degi, 0, NN * sizeof(int), stream);
    if (has_rank) {
        k_hist_rank<<<(NE + 255) / 256, 256, 0, stream>>>(dst, degi, rank, NE);
    } else {
        hipMemsetAsync(cnt, 0, NN * sizeof(int), stream);
        k_hist<<<NCHUNK * NPART, 256, 0, stream>>>(dst, degi, NE);
    }
    k_dinv<<<(NN + 255) / 256, 256, 0, stream>>>(degi, dinv, NN);
    k_scan_local<<<SNB, 256, 0, stream>>>(degi, rowptr, part);
    k_scan_part<<<1, 128, 0, stream>>>(part);
    k_scan_add<<<(NN + 255) / 256, 256, 0, stream>>>(rowptr, part);
    if (has_rank) {
        k_fill_rank<<<(NE + 255) / 256, 256, 0, stream>>>(src, dst, rank, rowptr, csr, NE);
    } else {
        k_fill<<<NCHUNK * NPART, 256, 0, stream>>>(src, dst, rowptr, cnt, csr, NE);
    }

    // ---- layer 1: Bb = bf16(x@W1); A = relu(agg(Bb)+b1) ----
    k_gemm_bf<<<(NN + 63) / 64, 256, 0, stream>>>(x, W1, Bb, NN);
    k_reduce<<<(NN + 3) / 4, 256, 0, stream>>>(Bb, rowptr, csr, dinv, b1, A, nullptr, 1);

    // ---- layer 2: Bb = bf16(A@W2); out = agg(Bb)+b2 ----
    k_gemm_bf<<<(NN + 63) / 64, 256, 0, stream>>>(A, W2, Bb, NN);
    if (big_ws) {
        k_reduce<<<(NN + 3) / 4, 256, 0, stream>>>(Bb, rowptr, csr, dinv, b2, A, B, 0);
    } else {
        k_reduce<<<(NN + 3) / 4, 256, 0, stream>>>(Bb, rowptr, csr, dinv, b2, A, nullptr, 0);
        k_copy4<<<(NN * DD / 4 + 255) / 256, 256, 0, stream>>>((const float4*)A, (float4*)B, NN * DD / 4);
    }
}

// Round 7
// 294.200 us; speedup vs baseline: 2.8195x; 1.1126x over previous
//
#include <hip/hip_runtime.h>

#define NN 100000
#define NE 1200000
#define DD 64
#define NPART 8
#define PSZ (NN / NPART)
#define EPB 4096
#define NCHUNK ((NE + EPB - 1) / EPB)
#define SCH 1024                                // scan chunk (elements per block)
#define SNB ((NN + SCH - 1) / SCH)              // 98 scan blocks

// bf16 helpers
static __device__ __forceinline__ unsigned short f2bf(float f) {
    unsigned int u = __float_as_uint(f);
    u += 0x7fffu + ((u >> 16) & 1u);
    return (unsigned short)(u >> 16);
}
static __device__ __forceinline__ float bf_lo(unsigned int u) {   // low bf16 of a packed pair
    return __uint_as_float(u << 16);
}
static __device__ __forceinline__ float bf_hi(unsigned int u) {   // high bf16
    return __uint_as_float(u & 0xffff0000u);
}

// ---------------- histogram + rank (atomic return value = rank in dst segment) ----------------
__global__ void k_hist_rank(const int* __restrict__ dst, int* __restrict__ degi,
                            int* __restrict__ rank, int ne) {
    int i = blockIdx.x * blockDim.x + threadIdx.x;
    if (i < ne) rank[i] = atomicAdd(&degi[dst[i]], 1);
}

// fallback partitioned histogram (no rank buffer)
__global__ __launch_bounds__(256) void k_hist(const int* __restrict__ dst,
                                              int* __restrict__ degi, int ne) {
    int part = blockIdx.x & (NPART - 1);
    int lo = part * PSZ, hi = lo + PSZ;
    int beg = (blockIdx.x >> 3) * EPB;
    int end = min(beg + EPB, ne);
    for (int e = beg + (int)threadIdx.x; e < end; e += 256) {
        int d = dst[e];
        if (d >= lo && d < hi) atomicAdd(&degi[d], 1);
    }
}

// ---------------- parallel exclusive scan (+ fused dinv) ----------------
__global__ __launch_bounds__(256) void k_scan_local(const int* __restrict__ degi,
                                                    int* __restrict__ rowptr,
                                                    int* __restrict__ part,
                                                    float* __restrict__ dinv) {
    __shared__ int wsum[4];
    int t = threadIdx.x;
    int idx = blockIdx.x * SCH + t * 4;
    int d0 = 0, d1 = 0, d2 = 0, d3 = 0;
    if (idx + 3 < NN) {
        int4 v = *(const int4*)&degi[idx];
        d0 = v.x; d1 = v.y; d2 = v.z; d3 = v.w;
        float4 dv;
        dv.x = rsqrtf((float)d0 + 1.0f);
        dv.y = rsqrtf((float)d1 + 1.0f);
        dv.z = rsqrtf((float)d2 + 1.0f);
        dv.w = rsqrtf((float)d3 + 1.0f);
        *(float4*)&dinv[idx] = dv;
    } else {
        if (idx     < NN) { d0 = degi[idx];     dinv[idx]     = rsqrtf((float)d0 + 1.0f); }
        if (idx + 1 < NN) { d1 = degi[idx + 1]; dinv[idx + 1] = rsqrtf((float)d1 + 1.0f); }
        if (idx + 2 < NN) { d2 = degi[idx + 2]; dinv[idx + 2] = rsqrtf((float)d2 + 1.0f); }
        if (idx + 3 < NN) { d3 = degi[idx + 3]; dinv[idx + 3] = rsqrtf((float)d3 + 1.0f); }
    }
    int s = d0 + d1 + d2 + d3;
    int lane = t & 63;
    int incl = s;
#pragma unroll
    for (int off = 1; off < 64; off <<= 1) {
        int v = __shfl_up(incl, off);
        if (lane >= off) incl += v;
    }
    int wv = t >> 6;
    if (lane == 63) wsum[wv] = incl;
    __syncthreads();
    int woff = 0;
#pragma unroll
    for (int i = 0; i < 4; ++i) if (i < wv) woff += wsum[i];
    int excl = woff + incl - s;
    if (idx     < NN) rowptr[idx]     = excl;
    if (idx + 1 < NN) rowptr[idx + 1] = excl + d0;
    if (idx + 2 < NN) rowptr[idx + 2] = excl + d0 + d1;
    if (idx + 3 < NN) rowptr[idx + 3] = excl + d0 + d1 + d2;
    if (t == 255) part[blockIdx.x] = woff + incl;
}

__global__ __launch_bounds__(128) void k_scan_part(int* __restrict__ part) {
    __shared__ int sm[128];
    int t = threadIdx.x;
    int v = (t < SNB) ? part[t] : 0;
    sm[t] = v;
    __syncthreads();
    for (int off = 1; off < 128; off <<= 1) {
        int add = (t >= off) ? sm[t - off] : 0;
        __syncthreads();
        sm[t] += add;
        __syncthreads();
    }
    if (t < SNB) part[t] = sm[t] - v;
}

__global__ void k_scan_add(int* __restrict__ rowptr, const int* __restrict__ part) {
    int i = blockIdx.x * blockDim.x + threadIdx.x;
    if (i < NN) rowptr[i] += part[i >> 10];
    if (i == 0) rowptr[NN] = NE;
}

// ---------------- atomic-free CSR fill using precomputed ranks ----------------
__global__ void k_fill_rank(const int* __restrict__ src, const int* __restrict__ dst,
                            const int* __restrict__ rank, const int* __restrict__ rowptr,
                            int* __restrict__ csr_src, int ne) {
    int e = blockIdx.x * blockDim.x + threadIdx.x;
    if (e < ne) csr_src[rowptr[dst[e]] + rank[e]] = src[e];
}

// fallback partitioned fill with cursor atomics
__global__ __launch_bounds__(256) void k_fill(const int* __restrict__ src,
                                              const int* __restrict__ dst,
                                              const int* __restrict__ rowptr,
                                              int* __restrict__ cnt,
                                              int* __restrict__ csr_src, int ne) {
    int part = blockIdx.x & (NPART - 1);
    int lo = part * PSZ, hi = lo + PSZ;
    int beg = (blockIdx.x >> 3) * EPB;
    int end = min(beg + EPB, ne);
    for (int e = beg + (int)threadIdx.x; e < end; e += 256) {
        int d = dst[e];
        if (d >= lo && d < hi) {
            int pos = rowptr[d] + atomicAdd(&cnt[d], 1);
            csr_src[pos] = src[e];
        }
    }
}

// ---------------- GEMM: Hb_bf16[n,64] = X[n,64] @ W[64,64] ----------------
__global__ __launch_bounds__(256) void k_gemm_bf(const float* __restrict__ X,
                                                 const float* __restrict__ W,
                                                 unsigned short* __restrict__ Hb,
                                                 int nrows) {
    __shared__ float4 Ws4[64][16];
    __shared__ float  Xs[64][68];
    int tid = threadIdx.x;
    const float4* W4 = (const float4*)W;
    for (int i = tid; i < 64 * 16; i += 256) Ws4[i >> 4][i & 15] = W4[i];
    int row0 = blockIdx.x * 64;
    const float4* X4 = (const float4*)X;
    for (int i = tid; i < 64 * 16; i += 256) {
        int r = i >> 4, q = i & 15;
        int row = row0 + r;
        float4 v = make_float4(0.f, 0.f, 0.f, 0.f);
        if (row < nrows) v = X4[row * 16 + q];
        *((float4*)&Xs[r][q * 4]) = v;
    }
    __syncthreads();
    int c4 = tid & 15;
    int rg = tid >> 4;
    float4 acc0 = make_float4(0.f, 0.f, 0.f, 0.f);
    float4 acc1 = acc0, acc2 = acc0, acc3 = acc0;
#pragma unroll 4
    for (int k = 0; k < 64; ++k) {
        float4 w = Ws4[k][c4];
        float x0 = Xs[rg * 4 + 0][k];
        float x1 = Xs[rg * 4 + 1][k];
        float x2 = Xs[rg * 4 + 2][k];
        float x3 = Xs[rg * 4 + 3][k];
        acc0.x += x0 * w.x; acc0.y += x0 * w.y; acc0.z += x0 * w.z; acc0.w += x0 * w.w;
        acc1.x += x1 * w.x; acc1.y += x1 * w.y; acc1.z += x1 * w.z; acc1.w += x1 * w.w;
        acc2.x += x2 * w.x; acc2.y += x2 * w.y; acc2.z += x2 * w.z; acc2.w += x2 * w.w;
        acc3.x += x3 * w.x; acc3.y += x3 * w.y; acc3.z += x3 * w.z; acc3.w += x3 * w.w;
    }
    float4 accs[4] = {acc0, acc1, acc2, acc3};
#pragma unroll
    for (int i = 0; i < 4; ++i) {
        int row = row0 + rg * 4 + i;
        if (row < nrows) {
            ushort4 o;
            o.x = f2bf(accs[i].x); o.y = f2bf(accs[i].y);
            o.z = f2bf(accs[i].z); o.w = f2bf(accs[i].w);
            *((ushort4*)&Hb[row * 64 + c4 * 4]) = o;
        }
    }
}

// ---------------- MLP-maximized fused reduce ----------------
// Wave = 1 dst node. lane = eg*8+cg: eg=edge slot (8 edges/batch), cg=col group
// (8 bf16 = 16B). One Hb gather instruction = 8 rows = 16 lines in flight.
// Next batch's csr/dinv loads are software-pipelined over the current Hb gather.
__global__ __launch_bounds__(256) void k_reduce(const unsigned short* __restrict__ Hb,
                                                const int* __restrict__ rowptr,
                                                const int* __restrict__ csr_src,
                                                const float* __restrict__ dinv,
                                                const float* __restrict__ b,
                                                float* __restrict__ out0,
                                                float* __restrict__ out1,
                                                int do_relu) {
    int n = blockIdx.x * 4 + (threadIdx.x >> 6);
    if (n >= NN) return;
    int lane = threadIdx.x & 63;
    int eg = lane >> 3;        // edge slot 0..7
    int cg = lane & 7;         // col group 0..7 (cols cg*8 .. cg*8+7)
    float din = dinv[n];
    float acc[8];
#pragma unroll
    for (int j = 0; j < 8; ++j) acc[j] = 0.f;

    int e = rowptr[n], end = rowptr[n + 1];
    // prologue: batch-0 indices
    int idx = e + eg;
    bool v = idx < end;
    int s = v ? csr_src[idx] : 0;
    float cf = v ? dinv[s] * din : 0.f;

    while (e < end) {
        // issue this batch's Hb gather (8 rows x 128B)
        uint4 u = *(const uint4*)(Hb + (size_t)s * 64 + cg * 8);
        // pipeline: next batch's csr + dinv while Hb is in flight
        int e2 = e + 8;
        int idx2 = e2 + eg;
        bool v2 = idx2 < end;
        int s2 = v2 ? csr_src[idx2] : 0;
        float cf2 = v2 ? dinv[s2] * din : 0.f;
        // consume
        acc[0] += bf_lo(u.x) * cf;  acc[1] += bf_hi(u.x) * cf;
        acc[2] += bf_lo(u.y) * cf;  acc[3] += bf_hi(u.y) * cf;
        acc[4] += bf_lo(u.z) * cf;  acc[5] += bf_hi(u.z) * cf;
        acc[6] += bf_lo(u.w) * cf;  acc[7] += bf_hi(u.w) * cf;
        s = s2; cf = cf2; e = e2;
    }

    // combine the 8 edge slots (butterfly over eg bits = lane bits 3..5)
#pragma unroll
    for (int j = 0; j < 8; ++j) {
        acc[j] += __shfl_xor(acc[j], 8);
        acc[j] += __shfl_xor(acc[j], 16);
        acc[j] += __shfl_xor(acc[j], 32);
    }

    if (lane < 8) {            // eg==0 lanes: cg = lane
        uint4 us = *(const uint4*)(Hb + (size_t)n * 64 + cg * 8);
        float dd = din * din;
        float4 b0 = *(const float4*)(b + cg * 8);
        float4 b1 = *(const float4*)(b + cg * 8 + 4);
        float4 o0, o1;
        o0.x = acc[0] + bf_lo(us.x) * dd + b0.x;
        o0.y = acc[1] + bf_hi(us.x) * dd + b0.y;
        o0.z = acc[2] + bf_lo(us.y) * dd + b0.z;
        o0.w = acc[3] + bf_hi(us.y) * dd + b0.w;
        o1.x = acc[4] + bf_lo(us.z) * dd + b1.x;
        o1.y = acc[5] + bf_hi(us.z) * dd + b1.y;
        o1.z = acc[6] + bf_lo(us.w) * dd + b1.z;
        o1.w = acc[7] + bf_hi(us.w) * dd + b1.w;
        if (do_relu) {
            o0.x = fmaxf(o0.x, 0.f); o0.y = fmaxf(o0.y, 0.f);
            o0.z = fmaxf(o0.z, 0.f); o0.w = fmaxf(o0.w, 0.f);
            o1.x = fmaxf(o1.x, 0.f); o1.y = fmaxf(o1.y, 0.f);
            o1.z = fmaxf(o1.z, 0.f); o1.w = fmaxf(o1.w, 0.f);
        }
        *(float4*)(out0 + (size_t)n * 64 + cg * 8)     = o0;
        *(float4*)(out0 + (size_t)n * 64 + cg * 8 + 4) = o1;
        if (out1) {
            *(float4*)(out1 + (size_t)n * 64 + cg * 8)     = o0;
            *(float4*)(out1 + (size_t)n * 64 + cg * 8 + 4) = o1;
        }
    }
}

__global__ void k_copy4(const float4* __restrict__ in, float4* __restrict__ out, int n4) {
    int i = blockIdx.x * blockDim.x + threadIdx.x;
    if (i < n4) out[i] = in[i];
}

extern "C" void kernel_launch(void* const* d_in, const int* in_sizes, int n_in,
                              void* d_out, int out_size, void* d_ws, size_t ws_size,
                              hipStream_t stream) {
    const float* x  = (const float*)d_in[0];
    const int*   ei = (const int*)d_in[1];     // [2, NE]: src row then dst row
    const float* W1 = (const float*)d_in[2];
    const float* b1 = (const float*)d_in[3];
    const float* W2 = (const float*)d_in[4];
    const float* b2 = (const float*)d_in[5];
    const int* src = ei;
    const int* dst = ei + NE;

    float* A = (float*)d_out;                   // half 0: final h
    float* B = (float*)d_out + (size_t)NN * DD; // half 1: final h

    // ws layout
    char* w = (char*)d_ws;
    size_t off = 0;
    auto alloc = [&](size_t bytes) { void* p = w + off; off += (bytes + 255) & ~(size_t)255; return p; };
    float* dinv   = (float*)alloc(NN * sizeof(float));
    int*   degi   = (int*)  alloc(NN * sizeof(int));
    int*   cnt    = (int*)  alloc(NN * sizeof(int));
    int*   rowptr = (int*)  alloc((NN + 1) * sizeof(int));
    int*   part   = (int*)  alloc(512 * sizeof(int));
    int*   csr    = (int*)  alloc(NE * sizeof(int));
    int*   rank   = (int*)  alloc(NE * sizeof(int));
    size_t off_rank = off;
    unsigned short* Bb_ws = (unsigned short*)alloc((size_t)NN * DD * sizeof(unsigned short));
    size_t off_bb = off;
    bool has_rank = (ws_size >= off_rank);
    bool big_ws   = (ws_size >= off_bb);
    unsigned short* Bb = big_ws ? Bb_ws : (unsigned short*)B;

    // ---- CSR build ----
    hipMemsetAsync(degi, 0, NN * sizeof(int), stream);
    if (has_rank) {
        k_hist_rank<<<(NE + 255) / 256, 256, 0, stream>>>(dst, degi, rank, NE);
    } else {
        hipMemsetAsync(cnt, 0, NN * sizeof(int), stream);
        k_hist<<<NCHUNK * NPART, 256, 0, stream>>>(dst, degi, NE);
    }
    k_scan_local<<<SNB, 256, 0, stream>>>(degi, rowptr, part, dinv);
    k_scan_part<<<1, 128, 0, stream>>>(part);
    k_scan_add<<<(NN + 255) / 256, 256, 0, stream>>>(rowptr, part);
    if (has_rank) {
        k_fill_rank<<<(NE + 255) / 256, 256, 0, stream>>>(src, dst, rank, rowptr, csr, NE);
    } else {
        k_fill<<<NCHUNK * NPART, 256, 0, stream>>>(src, dst, rowptr, cnt, csr, NE);
    }

    // ---- layer 1: Bb = bf16(x@W1); A = relu(agg(Bb)+b1) ----
    k_gemm_bf<<<(NN + 63) / 64, 256, 0, stream>>>(x, W1, Bb, NN);
    k_reduce<<<(NN + 3) / 4, 256, 0, stream>>>(Bb, rowptr, csr, dinv, b1, A, nullptr, 1);

    // ---- layer 2: Bb = bf16(A@W2); out = agg(Bb)+b2 ----
    k_gemm_bf<<<(NN + 63) / 64, 256, 0, stream>>>(A, W2, Bb, NN);
    if (big_ws) {
        k_reduce<<<(NN + 3) / 4, 256, 0, stream>>>(Bb, rowptr, csr, dinv, b2, A, B, 0);
    } else {
        k_reduce<<<(NN + 3) / 4, 256, 0, stream>>>(Bb, rowptr, csr, dinv, b2, A, nullptr, 0);
        k_copy4<<<(NN * DD / 4 + 255) / 256, 256, 0, stream>>>((const float4*)A, (float4*)B, NN * DD / 4);
    }
}